// Round 17
// baseline (105.842 us; speedup 1.0000x reference)
//
#include <hip/hip_runtime.h>
#include <stdint.h>

typedef __attribute__((ext_vector_type(8))) short short8;        // 8 x bf16 (4 VGPRs)
typedef __attribute__((ext_vector_type(4))) float f32x4;
typedef __attribute__((ext_vector_type(4))) unsigned int u32x4;

#define MFMA16(a, b, c) __builtin_amdgcn_mfma_f32_16x16x32_bf16((a), (b), (c), 0, 0, 0)

#define GLOAD_LDS16(gsrc, ldst)                                                        \
    __builtin_amdgcn_global_load_lds(                                                  \
        (const __attribute__((address_space(1))) unsigned int*)(gsrc),                 \
        (__attribute__((address_space(3))) unsigned int*)(ldst), 16, 0, 0)

#define LOG2E 1.4426950408889634f

static __device__ __forceinline__ unsigned short f2bf(float f) {
    union { float f; unsigned int u; } v; v.f = f;
    unsigned int u = v.u;
    unsigned int r = 0x7fffu + ((u >> 16) & 1u);
    return (unsigned short)((u + r) >> 16);
}

static __device__ __forceinline__ float bf2f(unsigned short s) {
    union { unsigned int u; float f; } v; v.u = ((unsigned int)s) << 16;
    return v.f;
}

static __device__ __forceinline__ unsigned int cvt_pk_bf16(float lo, float hi) {
    unsigned int r;
    asm("v_cvt_pk_bf16_f32 %0, %1, %2" : "=v"(r) : "v"(lo), "v"(hi));
    return r;
}

// raw v_exp_f32: single instruction, exact for our |S| << 30 range (no OCML wrapper).
static __device__ __forceinline__ float fexp2(float x) {
#if __has_builtin(__builtin_amdgcn_exp2f)
    return __builtin_amdgcn_exp2f(x);
#else
    return exp2f(x);
#endif
}

// ---------------- Kernel 0: convert Wq|Wk|Wv f32 -> bf16 once ----------------
// Wb layout: [0,8192) Wq, [8192,16384) Wk, [16384,81920) Wv.
__global__ __launch_bounds__(256) void k_prepw(const float* __restrict__ Wq,
                                               const float* __restrict__ Wk,
                                               const float* __restrict__ Wv,
                                               unsigned short* __restrict__ Wb) {
    const int i = (blockIdx.x * 256 + threadIdx.x) * 4;
    const float* src; int off;
    if (i < 8192)       { src = Wq; off = i; }
    else if (i < 16384) { src = Wk; off = i - 8192; }
    else                { src = Wv; off = i - 16384; }
    const float4 v = *(const float4*)(src + off);
    ushort4 o;
    o.x = f2bf(v.x); o.y = f2bf(v.y); o.z = f2bf(v.z); o.w = f2bf(v.w);
    *(ushort4*)(Wb + i) = o;
}

// ---------------- Kernel 1: fused QKV projection, c-split for TLP ----------------
// grid (64, B, 2). Half 0: q,k + V rows [0,128); half 1: V rows [128,256).
// v epilogue: R12-form 64-i permutation (unit u = 4*is + g holds
// [V(32is+4g..+3), V(32is+16+4g..+3)]); jp = ((wv>>1)*4+(l15>>2))*8+(wv&1)*4+(l15&3).
__global__ __launch_bounds__(256) void k_qkv(const float* __restrict__ x,
                                             const unsigned short* __restrict__ Wb,
                                             const float* __restrict__ bq,
                                             const float* __restrict__ bk,
                                             const float* __restrict__ bv,
                                             unsigned short* __restrict__ qT,
                                             unsigned short* __restrict__ kT,
                                             unsigned short* __restrict__ vp) {
    const int b = blockIdx.y;
    const int nt = blockIdx.x;                    // 64-n tile
    const int h = blockIdx.z;                     // c-half of V
    const int lane = threadIdx.x & 63;
    const int wv = threadIdx.x >> 6;              // 0..3: wave's 16-n sub-tile
    const int l15 = lane & 15, g = lane >> 4;
    const int n0 = nt * 64;
    const int nw = n0 + wv * 16;

    const float* xb = x + (size_t)b * 1048576;    // [256 c][4096 n]
    const float* xs = xb + (size_t)(g * 8) * 4096 + nw + l15;

    const unsigned short* Wqb = Wb;
    const unsigned short* Wkb = Wb + 8192;
    const unsigned short* Wvb = Wb + 16384 + h * 32768;   // 128 rows x 256

    f32x4 aqk[4] = {};                            // q0,q1,k0,k1 (half 0 only)
    f32x4 av[8] = {};

#pragma unroll 2
    for (int k0 = 0; k0 < 256; k0 += 32) {
        const float* xp = xs + (size_t)k0 * 4096;
        float xv[8];
#pragma unroll
        for (int j = 0; j < 8; ++j) xv[j] = xp[(size_t)j * 4096];
        const u32x4 ux = {cvt_pk_bf16(xv[0], xv[1]), cvt_pk_bf16(xv[2], xv[3]),
                          cvt_pk_bf16(xv[4], xv[5]), cvt_pk_bf16(xv[6], xv[7])};
        const short8 xa = __builtin_bit_cast(short8, ux);

        if (h == 0) {
#pragma unroll
            for (int ot = 0; ot < 4; ++ot) {
                const unsigned short* wr = (ot < 2) ? (Wqb + (size_t)(ot * 16 + l15) * 256)
                                                    : (Wkb + (size_t)((ot - 2) * 16 + l15) * 256);
                const short8 wb8 = *(const short8*)(wr + k0 + g * 8);
                aqk[ot] = MFMA16(xa, wb8, aqk[ot]);
            }
        }
#pragma unroll
        for (int ct = 0; ct < 8; ++ct) {
            const short8 wv8 = *(const short8*)(Wvb + (size_t)(ct * 16 + l15) * 256 + k0 + g * 8);
            av[ct] = MFMA16(wv8, xa, av[ct]);
        }
    }

    if (h == 0) {
#pragma unroll
        for (int ot = 0; ot < 4; ++ot) {
            const int o = (ot & 1) * 16 + l15;
            const float bias = (ot < 2) ? bq[o] : bk[o];
            const float sc = (ot < 2) ? LOG2E : 1.0f;
            unsigned short* dst = (ot < 2) ? qT : kT;
#pragma unroll
            for (int r = 0; r < 4; ++r) {
                const int n = nw + g * 4 + r;
                dst[((size_t)b * 4096 + n) * 32 + o] = f2bf((aqk[ot][r] + bias) * sc);
            }
        }
    }
    const int jp = ((wv >> 1) * 4 + (l15 >> 2)) * 8 + (wv & 1) * 4 + (l15 & 3);
#pragma unroll
    for (int ct = 0; ct < 8; ++ct)
#pragma unroll
        for (int r = 0; r < 4; ++r) {
            const int c = h * 128 + ct * 16 + g * 4 + r;
            vp[((size_t)b * 256 + c) * 4096 + n0 + jp] = f2bf(av[ct][r] + bv[c]);
        }
}

// ---------------- Kernel 2: flash attention; 8 waves = 4 m-groups x 2 i-slices --------
// Block covers [256c x 128m] per 64-i tile. Wave (mg = wv>>1, sl = wv&1) computes
// m-range mg*32, i-slice sl*32 of each tile -> each V b128 read serves its wave only,
// but per-wave LDS reads halve (16/tile). Partner waves (sl 0/1) sum partial O + l
// via an end-of-kernel LDS reduction. No-max softmax (P = exp2(S), raw v_exp_f32).
// Custom MFMA k-order per 32-i slice: k-slot e of group g <-> i_loc = 4g+e (e<4),
// 16+4g+(e-4) (e>=4). vp pre-permuted (unit u = 4is+g); LDS slot = u ^ (c&7).
__global__ __launch_bounds__(512, 1) void k_attn(const unsigned short* __restrict__ qT,
                                                 const unsigned short* __restrict__ kT,
                                                 const unsigned short* __restrict__ vp,
                                                 unsigned short* __restrict__ Opart,
                                                 float* __restrict__ mll,
                                                 int ilen) {
    // [2 buf][256 c][64 i'] bf16; 16B chunk (c, slot) holds unit u = slot ^ (c&7). 64 KiB.
    __shared__ __align__(16) unsigned short vlds[2 * 16384];

    const int b = blockIdx.y;
    const int mt = blockIdx.x;
    const int sp = blockIdx.z;
    const int tid = threadIdx.x;
    const int lane = tid & 63;
    const int wv = tid >> 6;                      // 0..7
    const int mg = wv >> 1, sl = wv & 1;
    const int l15 = lane & 15, g = lane >> 4;
    const int m_base = mt * 128 + mg * 32;
    const int i_start = sp * ilen;
    const int T = ilen >> 6;

    const unsigned short* qTb = qT + (size_t)b * 131072;
    const unsigned short* vpb = vp + (size_t)b * 1048576;

    const short8 qkB0 = *(const short8*)(kT + ((size_t)b * 4096 + m_base + l15) * 32 + g * 8);
    const short8 qkB1 = *(const short8*)(kT + ((size_t)b * 4096 + m_base + 16 + l15) * 32 + g * 8);

    // staging (8 waves x 4 instr): c = 32*wv + 8*s_ + (lane>>3), slot = lane&7;
    // source pre-swizzled: jd = (lane&7) ^ ((lane>>3)&7)  (lane-only -> hoistable).
    const int jd = (lane & 7) ^ ((lane >> 3) & 7);
    const unsigned short* vsrc = vpb + (size_t)(32 * wv + (lane >> 3)) * 4096 + i_start + jd * 8;
    const int ldst0 = wv * 2048;                  // element offset within buffer

#define STAGE(bufsel, ioff)                                                             \
    do {                                                                                \
        _Pragma("unroll")                                                               \
        for (int s_ = 0; s_ < 4; ++s_)                                                  \
            GLOAD_LDS16(vsrc + (size_t)s_ * 32768 + (ioff),                             \
                        vlds + (bufsel) * 16384 + ldst0 + s_ * 512);                    \
    } while (0)

    // PV A-frag: one b128 per ct; row c = ct*16 + l15; unit u = 4*sl + g;
    // slot = u ^ (l15&7); ct stride 1024 elements.
    const int rdA = l15 * 64 + (((4 * sl + g) ^ (l15 & 7)) << 3);

    // q rows: wave's i-slice = sl*32 within each 64-i tile
    const unsigned short* qp = qTb + (size_t)(i_start + sl * 32 + l15) * 32 + g * 8;

    f32x4 oacc[16][2] = {};
    float l_acc0 = 0.0f, l_acc1 = 0.0f;
    const f32x4 zf = {0.f, 0.f, 0.f, 0.f};

    STAGE(0, 0);
    __syncthreads();

    for (int t = 0; t < T; ++t) {
        const int cur = t & 1;
        if (t + 1 < T) STAGE(cur ^ 1, (t + 1) * 64);

        // ---- QK^T: 2 i-subtiles x 2 m-subtiles ----
        const short8 a0 = *(const short8*)(qp);
        const short8 a1 = *(const short8*)(qp + 512);
        qp += 2048;
        f32x4 P[2][2];
        P[0][0] = MFMA16(a0, qkB0, zf); P[0][1] = MFMA16(a0, qkB1, zf);
        P[1][0] = MFMA16(a1, qkB0, zf); P[1][1] = MFMA16(a1, qkB1, zf);

        // ---- P = exp2(S); per-lane l sums ----
        float s0 = 0.f, s1 = 0.f;
#pragma unroll
        for (int it = 0; it < 2; ++it)
#pragma unroll
            for (int r = 0; r < 4; ++r) {
                P[it][0][r] = fexp2(P[it][0][r]); s0 += P[it][0][r];
                P[it][1][r] = fexp2(P[it][1][r]); s1 += P[it][1][r];
            }
        l_acc0 += s0;
        l_acc1 += s1;

        // ---- pack PV B-frags (lane-local): words 0-1 = subtile 0, 2-3 = subtile 1 ----
        const u32x4 u0 = {cvt_pk_bf16(P[0][0][0], P[0][0][1]), cvt_pk_bf16(P[0][0][2], P[0][0][3]),
                          cvt_pk_bf16(P[1][0][0], P[1][0][1]), cvt_pk_bf16(P[1][0][2], P[1][0][3])};
        const u32x4 u1 = {cvt_pk_bf16(P[0][1][0], P[0][1][1]), cvt_pk_bf16(P[0][1][2], P[0][1][3]),
                          cvt_pk_bf16(P[1][1][0], P[1][1][1]), cvt_pk_bf16(P[1][1][2], P[1][1][3])};
        const short8 pb0 = __builtin_bit_cast(short8, u0);
        const short8 pb1 = __builtin_bit_cast(short8, u1);

        // ---- PV: one b128 V read per ct, each feeding 2 MFMAs ----
        const unsigned short* pA = vlds + cur * 16384 + rdA;
        __builtin_amdgcn_s_setprio(1);
#pragma unroll
        for (int ct = 0; ct < 16; ++ct) {
            const short8 va = *(const short8*)(pA + ct * 1024);
            oacc[ct][0] = MFMA16(va, pb0, oacc[ct][0]);
            oacc[ct][1] = MFMA16(va, pb1, oacc[ct][1]);
        }
        __builtin_amdgcn_s_setprio(0);

        if (t + 1 < T) __syncthreads();
    }
#undef STAGE

    // ---- cross-slice reduction: partner waves (mg, sl=1) -> (mg, sl=0) via LDS ----
    float* red = (float*)vlds;
    __syncthreads();
    if (sl == 1) {
#pragma unroll
        for (int ct = 0; ct < 8; ++ct)
#pragma unroll
            for (int ms = 0; ms < 2; ++ms)
                *(f32x4*)(red + mg * 4096 + (ct * 2 + ms) * 256 + lane * 4) = oacc[ct][ms];
    }
    __syncthreads();
    if (sl == 0) {
#pragma unroll
        for (int ct = 0; ct < 8; ++ct)
#pragma unroll
            for (int ms = 0; ms < 2; ++ms) {
                const f32x4 v = *(const f32x4*)(red + mg * 4096 + (ct * 2 + ms) * 256 + lane * 4);
                oacc[ct][ms] += v;
            }
    }
    __syncthreads();
    if (sl == 1) {
#pragma unroll
        for (int ct = 0; ct < 8; ++ct)
#pragma unroll
            for (int ms = 0; ms < 2; ++ms)
                *(f32x4*)(red + mg * 4096 + (ct * 2 + ms) * 256 + lane * 4) = oacc[ct + 8][ms];
    }
    __syncthreads();
    if (sl == 0) {
#pragma unroll
        for (int ct = 0; ct < 8; ++ct)
#pragma unroll
            for (int ms = 0; ms < 2; ++ms) {
                const f32x4 v = *(const f32x4*)(red + mg * 4096 + (ct * 2 + ms) * 256 + lane * 4);
                oacc[ct + 8][ms] += v;
            }
    }
    __syncthreads();
    if (sl == 1) {
        red[mg * 128 + lane * 2]     = l_acc0;
        red[mg * 128 + lane * 2 + 1] = l_acc1;
    }
    __syncthreads();

    if (sl == 0) {
        l_acc0 += red[mg * 128 + lane * 2];
        l_acc1 += red[mg * 128 + lane * 2 + 1];

        // ---- epilogue: raw partial O (bf16) and per-m l sums ----
        unsigned short* Ob = Opart + (size_t)(sp * 4 + b) * 1048576;
#pragma unroll
        for (int ct = 0; ct < 16; ++ct)
#pragma unroll
            for (int r = 0; r < 4; ++r) {
                const int c = ct * 16 + g * 4 + r;
                Ob[(size_t)c * 4096 + m_base + l15]      = f2bf(oacc[ct][0][r]);
                Ob[(size_t)c * 4096 + m_base + 16 + l15] = f2bf(oacc[ct][1][r]);
            }
        float l0 = l_acc0, l1 = l_acc1;
        l0 += __shfl_xor(l0, 16); l0 += __shfl_xor(l0, 32);
        l1 += __shfl_xor(l1, 16); l1 += __shfl_xor(l1, 32);
        if (lane < 16) {
            const size_t mi = (size_t)(sp * 4 + b) * 4096 + m_base + l15;
            mll[mi]      = l0;
            mll[mi + 16] = l1;
        }
    }
}

// ---------------- Kernel 3: combine partials (pure sum) + gamma*O/L + x ----------------
// grid: 4*256*4096 / (256 threads * 8 elements) = 2048 blocks
__global__ __launch_bounds__(256) void k_combine(const unsigned short* __restrict__ Opart,
                                                 const float* __restrict__ mll,
                                                 const float* __restrict__ x,
                                                 const float* __restrict__ gamma,
                                                 float* __restrict__ out, int S) {
    const size_t e0 = ((size_t)blockIdx.x * 256 + threadIdx.x) * 8;   // < 4,194,304
    const int m0 = (int)(e0 & 4095);
    const int b = (int)(e0 >> 20);

    float L[8] = {}, O[8] = {};
    for (int s = 0; s < S; ++s) {
        const size_t base = (size_t)(s * 4 + b) * 4096 + m0;
        const float4 la = *(const float4*)(mll + base);
        const float4 lc = *(const float4*)(mll + base + 4);
        const short8 op = *(const short8*)(Opart + (size_t)s * 4194304 + e0);
        L[0] += la.x; O[0] += bf2f((unsigned short)op[0]);
        L[1] += la.y; O[1] += bf2f((unsigned short)op[1]);
        L[2] += la.z; O[2] += bf2f((unsigned short)op[2]);
        L[3] += la.w; O[3] += bf2f((unsigned short)op[3]);
        L[4] += lc.x; O[4] += bf2f((unsigned short)op[4]);
        L[5] += lc.y; O[5] += bf2f((unsigned short)op[5]);
        L[6] += lc.z; O[6] += bf2f((unsigned short)op[6]);
        L[7] += lc.w; O[7] += bf2f((unsigned short)op[7]);
    }

    const float g0 = gamma[0];
    const float4 x0 = *(const float4*)(x + e0);
    const float4 x1 = *(const float4*)(x + e0 + 4);
    float4 o0, o1;
    o0.x = g0 * O[0] / L[0] + x0.x; o0.y = g0 * O[1] / L[1] + x0.y;
    o0.z = g0 * O[2] / L[2] + x0.z; o0.w = g0 * O[3] / L[3] + x0.w;
    o1.x = g0 * O[4] / L[4] + x1.x; o1.y = g0 * O[5] / L[5] + x1.y;
    o1.z = g0 * O[6] / L[6] + x1.z; o1.w = g0 * O[7] / L[7] + x1.w;
    *(float4*)(out + e0) = o0;
    *(float4*)(out + e0 + 4) = o1;
}

extern "C" void kernel_launch(void* const* d_in, const int* in_sizes, int n_in,
                              void* d_out, int out_size, void* d_ws, size_t ws_size,
                              hipStream_t stream) {
    (void)in_sizes; (void)n_in; (void)out_size;
    const float* x     = (const float*)d_in[0];
    const float* Wq    = (const float*)d_in[1];
    const float* bq    = (const float*)d_in[2];
    const float* Wk    = (const float*)d_in[3];
    const float* bk    = (const float*)d_in[4];
    const float* Wv    = (const float*)d_in[5];
    const float* bv    = (const float*)d_in[6];
    const float* gamma = (const float*)d_in[7];
    float* out = (float*)d_out;

    unsigned short* qT = (unsigned short*)d_ws;                       // 4*4096*32 bf16
    unsigned short* kT = qT + (size_t)4 * 4096 * 32;                  // 4*4096*32
    unsigned short* vp = kT + (size_t)4 * 4096 * 32;                  // 4*256*4096
    unsigned short* Wb = vp + (size_t)4 * 256 * 4096;                 // 81920 bf16
    unsigned short* Opart = Wb + 81920;                               // S * 4*256*4096 bf16

    const size_t base_el = 2 * (size_t)4 * 4096 * 32 + (size_t)4 * 256 * 4096 + 81920;
    auto need = [&](int s) {
        return (base_el + (size_t)s * 4194304) * 2 + (size_t)s * 16384 * 4;
    };
    const int S = (need(4) <= ws_size) ? 4 : (need(2) <= ws_size) ? 2 : 1;
    float* mll = (float*)(Opart + (size_t)S * 4194304);

    k_prepw<<<dim3(80), 256, 0, stream>>>(Wq, Wk, Wv, Wb);
    k_qkv<<<dim3(64, 4, 2), 256, 0, stream>>>(x, Wb, bq, bk, bv, qT, kT, vp);
    k_attn<<<dim3(32, 4, S), 512, 0, stream>>>(qT, kT, vp, Opart, mll, 4096 / S);
    k_combine<<<dim3(2048), 256, 0, stream>>>(Opart, mll, x, gamma, out, S);
}

// Round 18
// 83.737 us; speedup vs baseline: 1.2640x; 1.2640x over previous
//
#include <hip/hip_runtime.h>
#include <stdint.h>

typedef __attribute__((ext_vector_type(8))) short short8;        // 8 x bf16 (4 VGPRs)
typedef __attribute__((ext_vector_type(4))) float f32x4;
typedef __attribute__((ext_vector_type(4))) unsigned int u32x4;

#define MFMA16(a, b, c) __builtin_amdgcn_mfma_f32_16x16x32_bf16((a), (b), (c), 0, 0, 0)

#define GLOAD_LDS16(gsrc, ldst)                                                        \
    __builtin_amdgcn_global_load_lds(                                                  \
        (const __attribute__((address_space(1))) unsigned int*)(gsrc),                 \
        (__attribute__((address_space(3))) unsigned int*)(ldst), 16, 0, 0)

#define LOG2E 1.4426950408889634f

static __device__ __forceinline__ unsigned short f2bf(float f) {
    union { float f; unsigned int u; } v; v.f = f;
    unsigned int u = v.u;
    unsigned int r = 0x7fffu + ((u >> 16) & 1u);
    return (unsigned short)((u + r) >> 16);
}

static __device__ __forceinline__ float bf2f(unsigned short s) {
    union { unsigned int u; float f; } v; v.u = ((unsigned int)s) << 16;
    return v.f;
}

static __device__ __forceinline__ unsigned int cvt_pk_bf16(float lo, float hi) {
    unsigned int r;
    asm("v_cvt_pk_bf16_f32 %0, %1, %2" : "=v"(r) : "v"(lo), "v"(hi));
    return r;
}

// raw v_exp_f32: single instruction, exact for our |S| << 30 range (no OCML wrapper).
static __device__ __forceinline__ float fexp2(float x) {
#if __has_builtin(__builtin_amdgcn_exp2f)
    return __builtin_amdgcn_exp2f(x);
#else
    return exp2f(x);
#endif
}

// ---------------- Kernel 0: convert Wq|Wk|Wv f32 -> bf16 once ----------------
// Wb layout: [0,8192) Wq, [8192,16384) Wk, [16384,81920) Wv.
__global__ __launch_bounds__(256) void k_prepw(const float* __restrict__ Wq,
                                               const float* __restrict__ Wk,
                                               const float* __restrict__ Wv,
                                               unsigned short* __restrict__ Wb) {
    const int i = (blockIdx.x * 256 + threadIdx.x) * 4;
    const float* src; int off;
    if (i < 8192)       { src = Wq; off = i; }
    else if (i < 16384) { src = Wk; off = i - 8192; }
    else                { src = Wv; off = i - 16384; }
    const float4 v = *(const float4*)(src + off);
    ushort4 o;
    o.x = f2bf(v.x); o.y = f2bf(v.y); o.z = f2bf(v.z); o.w = f2bf(v.w);
    *(ushort4*)(Wb + i) = o;
}

// ---------------- Kernel 1: fused QKV projection, c-split for TLP ----------------
// grid (64, B, 2). Half 0: q,k + V rows [0,128); half 1: V rows [128,256).
// v epilogue: 64-i permutation (unit u = 4*is + g holds
// [V(32is+4g..+3), V(32is+16+4g..+3)]); jp = ((wv>>1)*4+(l15>>2))*8+(wv&1)*4+(l15&3).
__global__ __launch_bounds__(256) void k_qkv(const float* __restrict__ x,
                                             const unsigned short* __restrict__ Wb,
                                             const float* __restrict__ bq,
                                             const float* __restrict__ bk,
                                             const float* __restrict__ bv,
                                             unsigned short* __restrict__ qT,
                                             unsigned short* __restrict__ kT,
                                             unsigned short* __restrict__ vp) {
    const int b = blockIdx.y;
    const int nt = blockIdx.x;                    // 64-n tile
    const int h = blockIdx.z;                     // c-half of V
    const int lane = threadIdx.x & 63;
    const int wv = threadIdx.x >> 6;              // 0..3: wave's 16-n sub-tile
    const int l15 = lane & 15, g = lane >> 4;
    const int n0 = nt * 64;
    const int nw = n0 + wv * 16;

    const float* xb = x + (size_t)b * 1048576;    // [256 c][4096 n]
    const float* xs = xb + (size_t)(g * 8) * 4096 + nw + l15;

    const unsigned short* Wqb = Wb;
    const unsigned short* Wkb = Wb + 8192;
    const unsigned short* Wvb = Wb + 16384 + h * 32768;   // 128 rows x 256

    f32x4 aqk[4] = {};                            // q0,q1,k0,k1 (half 0 only)
    f32x4 av[8] = {};

#pragma unroll 2
    for (int k0 = 0; k0 < 256; k0 += 32) {
        const float* xp = xs + (size_t)k0 * 4096;
        float xv[8];
#pragma unroll
        for (int j = 0; j < 8; ++j) xv[j] = xp[(size_t)j * 4096];
        const u32x4 ux = {cvt_pk_bf16(xv[0], xv[1]), cvt_pk_bf16(xv[2], xv[3]),
                          cvt_pk_bf16(xv[4], xv[5]), cvt_pk_bf16(xv[6], xv[7])};
        const short8 xa = __builtin_bit_cast(short8, ux);

        if (h == 0) {
#pragma unroll
            for (int ot = 0; ot < 4; ++ot) {
                const unsigned short* wr = (ot < 2) ? (Wqb + (size_t)(ot * 16 + l15) * 256)
                                                    : (Wkb + (size_t)((ot - 2) * 16 + l15) * 256);
                const short8 wb8 = *(const short8*)(wr + k0 + g * 8);
                aqk[ot] = MFMA16(xa, wb8, aqk[ot]);
            }
        }
#pragma unroll
        for (int ct = 0; ct < 8; ++ct) {
            const short8 wv8 = *(const short8*)(Wvb + (size_t)(ct * 16 + l15) * 256 + k0 + g * 8);
            av[ct] = MFMA16(wv8, xa, av[ct]);
        }
    }

    if (h == 0) {
#pragma unroll
        for (int ot = 0; ot < 4; ++ot) {
            const int o = (ot & 1) * 16 + l15;
            const float bias = (ot < 2) ? bq[o] : bk[o];
            const float sc = (ot < 2) ? LOG2E : 1.0f;
            unsigned short* dst = (ot < 2) ? qT : kT;
#pragma unroll
            for (int r = 0; r < 4; ++r) {
                const int n = nw + g * 4 + r;
                dst[((size_t)b * 4096 + n) * 32 + o] = f2bf((aqk[ot][r] + bias) * sc);
            }
        }
    }
    const int jp = ((wv >> 1) * 4 + (l15 >> 2)) * 8 + (wv & 1) * 4 + (l15 & 3);
#pragma unroll
    for (int ct = 0; ct < 8; ++ct)
#pragma unroll
        for (int r = 0; r < 4; ++r) {
            const int c = h * 128 + ct * 16 + g * 4 + r;
            vp[((size_t)b * 256 + c) * 4096 + n0 + jp] = f2bf(av[ct][r] + bv[c]);
        }
}

// ---------------- Kernel 2: flash attention (R15 structure + q cross-tile prefetch) ---
// No-max softmax: P = exp2(S) via raw v_exp_f32. Custom MFMA k-order:
//   e<4:  i = 32*is + 4g + e        e>=4: i = 32*is + 16 + 4g + (e-4)
// vp pre-permuted so unit u=4is+g is contiguous 16B; LDS slot = u ^ (c&7) (0-conflict).
// Next tile's q fragments load before PV so their global latency hides under PV.
__global__ __launch_bounds__(256, 2) void k_attn(const unsigned short* __restrict__ qT,
                                                 const unsigned short* __restrict__ kT,
                                                 const unsigned short* __restrict__ vp,
                                                 unsigned short* __restrict__ Opart,
                                                 float* __restrict__ mll,
                                                 int ilen) {
    // [2 buf][256 c][64 i'] bf16; 16B chunk (c, slot) holds unit u = slot ^ (c&7). 64 KiB.
    __shared__ __align__(16) unsigned short vlds[2 * 16384];

    const int b = blockIdx.y;
    const int mt = blockIdx.x;
    const int sp = blockIdx.z;
    const int tid = threadIdx.x;
    const int lane = tid & 63;
    const int wv = tid >> 6;
    const int l15 = lane & 15, g = lane >> 4;
    const int m_base = mt * 128 + wv * 32;
    const int i_start = sp * ilen;
    const int T = ilen >> 6;

    const unsigned short* qTb = qT + (size_t)b * 131072;
    const unsigned short* vpb = vp + (size_t)b * 1048576;

    const short8 qkB0 = *(const short8*)(kT + ((size_t)b * 4096 + m_base + l15) * 32 + g * 8);
    const short8 qkB1 = *(const short8*)(kT + ((size_t)b * 4096 + m_base + 16 + l15) * 32 + g * 8);

    // staging: lane -> (c = 64wv + 8s + (lane>>3), slot jc = lane&7); source pre-swizzled:
    // jd = jc ^ (c&7) = (lane&7) ^ ((lane>>3)&7)  (lane-only -> hoistable pointer).
    const int jd = (lane & 7) ^ ((lane >> 3) & 7);
    const unsigned short* vsrc = vpb + (size_t)(64 * wv + (lane >> 3)) * 4096 + i_start + jd * 8;
    const int ldst0 = wv * 4096;

#define STAGE(bufsel, ioff)                                                             \
    do {                                                                                \
        _Pragma("unroll")                                                               \
        for (int s_ = 0; s_ < 8; ++s_)                                                  \
            GLOAD_LDS16(vsrc + (size_t)s_ * 32768 + (ioff),                             \
                        vlds + (bufsel) * 16384 + ldst0 + s_ * 512);                    \
    } while (0)

    // PV A-frag: one b128 per (is, ct); slot(is) = (4is+g) ^ (l15&7); ct stride 1024.
    const int rdA = l15 * 64 + ((g ^ (l15 & 7)) << 3);            // is = 0
    const int rdB = l15 * 64 + (((4 + g) ^ (l15 & 7)) << 3);      // is = 1

    const unsigned short* qp = qTb + (size_t)(i_start + l15) * 32 + g * 8;

    f32x4 oacc[16][2] = {};
    float l_acc0 = 0.0f, l_acc1 = 0.0f;
    const f32x4 zf = {0.f, 0.f, 0.f, 0.f};

    // prologue: stage tile 0 and load tile 0's q fragments
    STAGE(0, 0);
    short8 qa0 = *(const short8*)(qp);
    short8 qa1 = *(const short8*)(qp + 512);
    short8 qa2 = *(const short8*)(qp + 1024);
    short8 qa3 = *(const short8*)(qp + 1536);
    qp += 2048;
    __syncthreads();

    for (int t = 0; t < T; ++t) {
        const int cur = t & 1;
        if (t + 1 < T) STAGE(cur ^ 1, (t + 1) * 64);

        // ---- QK^T: 4 i-subtiles x 2 m-subtiles (q fragments preloaded) ----
        f32x4 P[4][2];
        P[0][0] = MFMA16(qa0, qkB0, zf); P[0][1] = MFMA16(qa0, qkB1, zf);
        P[1][0] = MFMA16(qa1, qkB0, zf); P[1][1] = MFMA16(qa1, qkB1, zf);
        P[2][0] = MFMA16(qa2, qkB0, zf); P[2][1] = MFMA16(qa2, qkB1, zf);
        P[3][0] = MFMA16(qa3, qkB0, zf); P[3][1] = MFMA16(qa3, qkB1, zf);

        // ---- P = exp2(S) via raw v_exp_f32; per-lane l sums ----
        float s00 = 0.f, s01 = 0.f, s10 = 0.f, s11 = 0.f;
#pragma unroll
        for (int it = 0; it < 4; ++it)
#pragma unroll
            for (int r = 0; r < 4; ++r) {
                P[it][0][r] = fexp2(P[it][0][r]);
                P[it][1][r] = fexp2(P[it][1][r]);
                if (it < 2) { s00 += P[it][0][r]; s01 += P[it][1][r]; }
                else        { s10 += P[it][0][r]; s11 += P[it][1][r]; }
            }
        l_acc0 += s00 + s10;
        l_acc1 += s01 + s11;

        // ---- pack P B-frags (lane-local) ----
        const u32x4 u00 = {cvt_pk_bf16(P[0][0][0], P[0][0][1]), cvt_pk_bf16(P[0][0][2], P[0][0][3]),
                           cvt_pk_bf16(P[1][0][0], P[1][0][1]), cvt_pk_bf16(P[1][0][2], P[1][0][3])};
        const u32x4 u01 = {cvt_pk_bf16(P[0][1][0], P[0][1][1]), cvt_pk_bf16(P[0][1][2], P[0][1][3]),
                           cvt_pk_bf16(P[1][1][0], P[1][1][1]), cvt_pk_bf16(P[1][1][2], P[1][1][3])};
        const u32x4 u10 = {cvt_pk_bf16(P[2][0][0], P[2][0][1]), cvt_pk_bf16(P[2][0][2], P[2][0][3]),
                           cvt_pk_bf16(P[3][0][0], P[3][0][1]), cvt_pk_bf16(P[3][0][2], P[3][0][3])};
        const u32x4 u11 = {cvt_pk_bf16(P[2][1][0], P[2][1][1]), cvt_pk_bf16(P[2][1][2], P[2][1][3]),
                           cvt_pk_bf16(P[3][1][0], P[3][1][1]), cvt_pk_bf16(P[3][1][2], P[3][1][3])};
        const short8 pb00 = __builtin_bit_cast(short8, u00);
        const short8 pb01 = __builtin_bit_cast(short8, u01);
        const short8 pb10 = __builtin_bit_cast(short8, u10);
        const short8 pb11 = __builtin_bit_cast(short8, u11);

        // ---- prefetch next tile's q fragments (latency hides under PV) ----
        short8 qn0, qn1, qn2, qn3;
        if (t + 1 < T) {
            qn0 = *(const short8*)(qp);
            qn1 = *(const short8*)(qp + 512);
            qn2 = *(const short8*)(qp + 1024);
            qn3 = *(const short8*)(qp + 1536);
            qp += 2048;
        }

        // ---- PV: one b128 V read per (is, ct), each feeding 2 MFMAs ----
        const unsigned short* vbase = vlds + cur * 16384;
        const unsigned short* pA = vbase + rdA;
        const unsigned short* pB = vbase + rdB;
        __builtin_amdgcn_s_setprio(1);
#pragma unroll
        for (int ct = 0; ct < 16; ++ct) {
            const short8 va0 = *(const short8*)(pA + ct * 1024);
            const short8 va1 = *(const short8*)(pB + ct * 1024);
            oacc[ct][0] = MFMA16(va0, pb00, oacc[ct][0]);
            oacc[ct][1] = MFMA16(va0, pb01, oacc[ct][1]);
            oacc[ct][0] = MFMA16(va1, pb10, oacc[ct][0]);
            oacc[ct][1] = MFMA16(va1, pb11, oacc[ct][1]);
        }
        __builtin_amdgcn_s_setprio(0);

        if (t + 1 < T) {
            qa0 = qn0; qa1 = qn1; qa2 = qn2; qa3 = qn3;
            __syncthreads();
        }
    }
#undef STAGE

    // ---- epilogue: raw partial O (bf16) and per-m l sums ----
    unsigned short* Ob = Opart + (size_t)(sp * 4 + b) * 1048576;
#pragma unroll
    for (int ct = 0; ct < 16; ++ct)
#pragma unroll
        for (int r = 0; r < 4; ++r) {
            const int c = ct * 16 + g * 4 + r;
            Ob[(size_t)c * 4096 + m_base + l15]      = f2bf(oacc[ct][0][r]);
            Ob[(size_t)c * 4096 + m_base + 16 + l15] = f2bf(oacc[ct][1][r]);
        }
    float l0 = l_acc0, l1 = l_acc1;
    l0 += __shfl_xor(l0, 16); l0 += __shfl_xor(l0, 32);
    l1 += __shfl_xor(l1, 16); l1 += __shfl_xor(l1, 32);
    if (lane < 16) {
        const size_t mi = (size_t)(sp * 4 + b) * 4096 + m_base + l15;
        mll[mi]      = l0;
        mll[mi + 16] = l1;
    }
}

// ---------------- Kernel 3: combine partials (pure sum) + gamma*O/L + x ----------------
// grid: 4*256*4096 / (256 threads * 8 elements) = 2048 blocks
__global__ __launch_bounds__(256) void k_combine(const unsigned short* __restrict__ Opart,
                                                 const float* __restrict__ mll,
                                                 const float* __restrict__ x,
                                                 const float* __restrict__ gamma,
                                                 float* __restrict__ out, int S) {
    const size_t e0 = ((size_t)blockIdx.x * 256 + threadIdx.x) * 8;   // < 4,194,304
    const int m0 = (int)(e0 & 4095);
    const int b = (int)(e0 >> 20);

    float L[8] = {}, O[8] = {};
    for (int s = 0; s < S; ++s) {
        const size_t base = (size_t)(s * 4 + b) * 4096 + m0;
        const float4 la = *(const float4*)(mll + base);
        const float4 lc = *(const float4*)(mll + base + 4);
        const short8 op = *(const short8*)(Opart + (size_t)s * 4194304 + e0);
        L[0] += la.x; O[0] += bf2f((unsigned short)op[0]);
        L[1] += la.y; O[1] += bf2f((unsigned short)op[1]);
        L[2] += la.z; O[2] += bf2f((unsigned short)op[2]);
        L[3] += la.w; O[3] += bf2f((unsigned short)op[3]);
        L[4] += lc.x; O[4] += bf2f((unsigned short)op[4]);
        L[5] += lc.y; O[5] += bf2f((unsigned short)op[5]);
        L[6] += lc.z; O[6] += bf2f((unsigned short)op[6]);
        L[7] += lc.w; O[7] += bf2f((unsigned short)op[7]);
    }

    const float g0 = gamma[0];
    const float4 x0 = *(const float4*)(x + e0);
    const float4 x1 = *(const float4*)(x + e0 + 4);
    float4 o0, o1;
    o0.x = g0 * O[0] / L[0] + x0.x; o0.y = g0 * O[1] / L[1] + x0.y;
    o0.z = g0 * O[2] / L[2] + x0.z; o0.w = g0 * O[3] / L[3] + x0.w;
    o1.x = g0 * O[4] / L[4] + x1.x; o1.y = g0 * O[5] / L[5] + x1.y;
    o1.z = g0 * O[6] / L[6] + x1.z; o1.w = g0 * O[7] / L[7] + x1.w;
    *(float4*)(out + e0) = o0;
    *(float4*)(out + e0 + 4) = o1;
}

extern "C" void kernel_launch(void* const* d_in, const int* in_sizes, int n_in,
                              void* d_out, int out_size, void* d_ws, size_t ws_size,
                              hipStream_t stream) {
    (void)in_sizes; (void)n_in; (void)out_size;
    const float* x     = (const float*)d_in[0];
    const float* Wq    = (const float*)d_in[1];
    const float* bq    = (const float*)d_in[2];
    const float* Wk    = (const float*)d_in[3];
    const float* bk    = (const float*)d_in[4];
    const float* Wv    = (const float*)d_in[5];
    const float* bv    = (const float*)d_in[6];
    const float* gamma = (const float*)d_in[7];
    float* out = (float*)d_out;

    unsigned short* qT = (unsigned short*)d_ws;                       // 4*4096*32 bf16
    unsigned short* kT = qT + (size_t)4 * 4096 * 32;                  // 4*4096*32
    unsigned short* vp = kT + (size_t)4 * 4096 * 32;                  // 4*256*4096
    unsigned short* Wb = vp + (size_t)4 * 256 * 4096;                 // 81920 bf16
    unsigned short* Opart = Wb + 81920;                               // S * 4*256*4096 bf16

    const size_t base_el = 2 * (size_t)4 * 4096 * 32 + (size_t)4 * 256 * 4096 + 81920;
    auto need = [&](int s) {
        return (base_el + (size_t)s * 4194304) * 2 + (size_t)s * 16384 * 4;
    };
    const int S = (need(4) <= ws_size) ? 4 : (need(2) <= ws_size) ? 2 : 1;
    float* mll = (float*)(Opart + (size_t)S * 4194304);

    k_prepw<<<dim3(80), 256, 0, stream>>>(Wq, Wk, Wv, Wb);
    k_qkv<<<dim3(64, 4, 2), 256, 0, stream>>>(x, Wb, bq, bk, bv, qT, kT, vp);
    k_attn<<<dim3(32, 4, S), 256, 0, stream>>>(qT, kT, vp, Opart, mll, 4096 / S);
    k_combine<<<dim3(2048), 256, 0, stream>>>(Opart, mll, x, gamma, out, S);
}

// Round 19
// 78.874 us; speedup vs baseline: 1.3419x; 1.0617x over previous
//
#include <hip/hip_runtime.h>
#include <stdint.h>

typedef __attribute__((ext_vector_type(8))) short short8;        // 8 x bf16 (4 VGPRs)
typedef __attribute__((ext_vector_type(4))) float f32x4;
typedef __attribute__((ext_vector_type(4))) unsigned int u32x4;
typedef __attribute__((ext_vector_type(2))) unsigned int u32x2;

#define MFMA16(a, b, c) __builtin_amdgcn_mfma_f32_16x16x32_bf16((a), (b), (c), 0, 0, 0)
#define MFMAF8(a, b, c) __builtin_amdgcn_mfma_f32_16x16x32_fp8_fp8((a), (b), (c), 0, 0, 0)

#define GLOAD_LDS16(gsrc, ldst)                                                        \
    __builtin_amdgcn_global_load_lds(                                                  \
        (const __attribute__((address_space(1))) unsigned int*)(gsrc),                 \
        (__attribute__((address_space(3))) unsigned int*)(ldst), 16, 0, 0)

#define LOG2E 1.4426950408889634f

static __device__ __forceinline__ unsigned short f2bf(float f) {
    union { float f; unsigned int u; } v; v.f = f;
    unsigned int u = v.u;
    unsigned int r = 0x7fffu + ((u >> 16) & 1u);
    return (unsigned short)((u + r) >> 16);
}

static __device__ __forceinline__ float bf2f(unsigned short s) {
    union { unsigned int u; float f; } v; v.u = ((unsigned int)s) << 16;
    return v.f;
}

static __device__ __forceinline__ unsigned int cvt_pk_bf16(float lo, float hi) {
    unsigned int r;
    asm("v_cvt_pk_bf16_f32 %0, %1, %2" : "=v"(r) : "v"(lo), "v"(hi));
    return r;
}

// raw v_exp_f32: single instruction, exact for our |S| << 30 range (no OCML wrapper).
static __device__ __forceinline__ float fexp2(float x) {
#if __has_builtin(__builtin_amdgcn_exp2f)
    return __builtin_amdgcn_exp2f(x);
#else
    return exp2f(x);
#endif
}

// ---- fp8 e4m3 (OCP) helpers ----
static __device__ __forceinline__ unsigned char f2e4m3_sw(float x) {   // fallback only
    unsigned u = __builtin_bit_cast(unsigned, x);
    unsigned s = (u >> 24) & 0x80u;
    float ax = fabsf(x);
    if (ax > 448.f) return (unsigned char)(s | 0x7e);
    if (ax < 0.0078125f) {                       // below 2^-7: denormal, ulp 2^-9
        int m = (int)(ax * 512.f + 0.5f);
        return (unsigned char)(s | m);
    }
    int e = (int)((u >> 23) & 0xff) - 127;
    unsigned m = (u >> 20) & 7;
    m += (u >> 19) & 1;                          // round
    unsigned enc = (unsigned)((e + 7) << 3) + m;
    if (enc > 0x7e) enc = 0x7e;
    return (unsigned char)(s | enc);
}

static __device__ __forceinline__ unsigned int pk_fp8_4(float a, float b, float c, float d) {
#if __has_builtin(__builtin_amdgcn_cvt_pk_fp8_f32)
    int r = 0;
    r = __builtin_amdgcn_cvt_pk_fp8_f32(a, b, r, false);
    r = __builtin_amdgcn_cvt_pk_fp8_f32(c, d, r, true);
    return (unsigned int)r;
#else
    return (unsigned)f2e4m3_sw(a) | ((unsigned)f2e4m3_sw(b) << 8) |
           ((unsigned)f2e4m3_sw(c) << 16) | ((unsigned)f2e4m3_sw(d) << 24);
#endif
}

static __device__ __forceinline__ unsigned char f2fp8(float v) {
#if __has_builtin(__builtin_amdgcn_cvt_pk_fp8_f32)
    return (unsigned char)(__builtin_amdgcn_cvt_pk_fp8_f32(v, v, 0, false) & 0xff);
#else
    return f2e4m3_sw(v);
#endif
}

// ---------------- Kernel 0: convert Wq|Wk|Wv f32 -> bf16 once ----------------
// Wb layout: [0,8192) Wq, [8192,16384) Wk, [16384,81920) Wv.
__global__ __launch_bounds__(256) void k_prepw(const float* __restrict__ Wq,
                                               const float* __restrict__ Wk,
                                               const float* __restrict__ Wv,
                                               unsigned short* __restrict__ Wb) {
    const int i = (blockIdx.x * 256 + threadIdx.x) * 4;
    const float* src; int off;
    if (i < 8192)       { src = Wq; off = i; }
    else if (i < 16384) { src = Wk; off = i - 8192; }
    else                { src = Wv; off = i - 16384; }
    const float4 v = *(const float4*)(src + off);
    ushort4 o;
    o.x = f2bf(v.x); o.y = f2bf(v.y); o.z = f2bf(v.z); o.w = f2bf(v.w);
    *(ushort4*)(Wb + i) = o;
}

// ---------------- Kernel 1: fused QKV projection, c-split for TLP ----------------
// grid (64, B, 2). Half 0: q,k + V rows [0,128); half 1: V rows [128,256).
// v epilogue: fp8 bytes into vp8 with the 64-i permutation (unit u = 4*is + g holds
// [V(32is+4g..+3), V(32is+16+4g..+3)]); jp = ((wv>>1)*4+(l15>>2))*8+(wv&1)*4+(l15&3).
__global__ __launch_bounds__(256) void k_qkv(const float* __restrict__ x,
                                             const unsigned short* __restrict__ Wb,
                                             const float* __restrict__ bq,
                                             const float* __restrict__ bk,
                                             const float* __restrict__ bv,
                                             unsigned short* __restrict__ qT,
                                             unsigned short* __restrict__ kT,
                                             unsigned char* __restrict__ vp8) {
    const int b = blockIdx.y;
    const int nt = blockIdx.x;                    // 64-n tile
    const int h = blockIdx.z;                     // c-half of V
    const int lane = threadIdx.x & 63;
    const int wv = threadIdx.x >> 6;              // 0..3: wave's 16-n sub-tile
    const int l15 = lane & 15, g = lane >> 4;
    const int n0 = nt * 64;
    const int nw = n0 + wv * 16;

    const float* xb = x + (size_t)b * 1048576;    // [256 c][4096 n]
    const float* xs = xb + (size_t)(g * 8) * 4096 + nw + l15;

    const unsigned short* Wqb = Wb;
    const unsigned short* Wkb = Wb + 8192;
    const unsigned short* Wvb = Wb + 16384 + h * 32768;   // 128 rows x 256

    f32x4 aqk[4] = {};                            // q0,q1,k0,k1 (half 0 only)
    f32x4 av[8] = {};

#pragma unroll 2
    for (int k0 = 0; k0 < 256; k0 += 32) {
        const float* xp = xs + (size_t)k0 * 4096;
        float xv[8];
#pragma unroll
        for (int j = 0; j < 8; ++j) xv[j] = xp[(size_t)j * 4096];
        const u32x4 ux = {cvt_pk_bf16(xv[0], xv[1]), cvt_pk_bf16(xv[2], xv[3]),
                          cvt_pk_bf16(xv[4], xv[5]), cvt_pk_bf16(xv[6], xv[7])};
        const short8 xa = __builtin_bit_cast(short8, ux);

        if (h == 0) {
#pragma unroll
            for (int ot = 0; ot < 4; ++ot) {
                const unsigned short* wr = (ot < 2) ? (Wqb + (size_t)(ot * 16 + l15) * 256)
                                                    : (Wkb + (size_t)((ot - 2) * 16 + l15) * 256);
                const short8 wb8 = *(const short8*)(wr + k0 + g * 8);
                aqk[ot] = MFMA16(xa, wb8, aqk[ot]);
            }
        }
#pragma unroll
        for (int ct = 0; ct < 8; ++ct) {
            const short8 wv8 = *(const short8*)(Wvb + (size_t)(ct * 16 + l15) * 256 + k0 + g * 8);
            av[ct] = MFMA16(wv8, xa, av[ct]);
        }
    }

    if (h == 0) {
#pragma unroll
        for (int ot = 0; ot < 4; ++ot) {
            const int o = (ot & 1) * 16 + l15;
            const float bias = (ot < 2) ? bq[o] : bk[o];
            const float sc = (ot < 2) ? LOG2E : 1.0f;
            unsigned short* dst = (ot < 2) ? qT : kT;
#pragma unroll
            for (int r = 0; r < 4; ++r) {
                const int n = nw + g * 4 + r;
                dst[((size_t)b * 4096 + n) * 32 + o] = f2bf((aqk[ot][r] + bias) * sc);
            }
        }
    }
    const int jp = ((wv >> 1) * 4 + (l15 >> 2)) * 8 + (wv & 1) * 4 + (l15 & 3);
#pragma unroll
    for (int ct = 0; ct < 8; ++ct)
#pragma unroll
        for (int r = 0; r < 4; ++r) {
            const int c = h * 128 + ct * 16 + g * 4 + r;
            vp8[((size_t)b * 256 + c) * 4096 + n0 + jp] = f2fp8(av[ct][r] + bv[c]);
        }
}

// ---------------- Kernel 2: flash attention; fp8 PV (V + P in e4m3) -------------------
// No-max softmax: P = exp2(S) via raw v_exp_f32. QK stays bf16. Custom MFMA k-order:
//   e<4:  i = 32*is + 4g + e        e>=4: i = 32*is + 16 + 4g + (e-4)
// vp8 pre-permuted so unit u=4is+g is a contiguous 8B fp8 group. LDS [2 buf][256c][64i]
// fp8 (16KB/buf); unit swizzle u' = u ^ (c&6) (pair-preserving -> 16B staging stays
// contiguous at source; b64 reads spread 4 accesses/bank = minimum).
__global__ __launch_bounds__(256, 2) void k_attn(const unsigned short* __restrict__ qT,
                                                 const unsigned short* __restrict__ kT,
                                                 const unsigned char* __restrict__ vp8,
                                                 unsigned short* __restrict__ Opart,
                                                 float* __restrict__ mll,
                                                 int ilen) {
    __shared__ __align__(16) unsigned char vlds[2 * 16384];

    const int b = blockIdx.y;
    const int mt = blockIdx.x;
    const int sp = blockIdx.z;
    const int tid = threadIdx.x;
    const int lane = tid & 63;
    const int wv = tid >> 6;
    const int l15 = lane & 15, g = lane >> 4;
    const int m_base = mt * 128 + wv * 32;
    const int i_start = sp * ilen;
    const int T = ilen >> 6;

    const unsigned short* qTb = qT + (size_t)b * 131072;
    const unsigned char* vpb8 = vp8 + (size_t)b * 1048576;

    const short8 qkB0 = *(const short8*)(kT + ((size_t)b * 4096 + m_base + l15) * 32 + g * 8);
    const short8 qkB1 = *(const short8*)(kT + ((size_t)b * 4096 + m_base + 16 + l15) * 32 + g * 8);

    // staging: instr s_ of wave wv covers rows c = 64wv + 16s_ + (lane>>2), slot-pair
    // sp = lane&3 (16B = 2 units); source pre-swizzled: units (2sp)^(c&6), +1.
    const unsigned char* vsrc = vpb8 + (size_t)(64 * wv + (lane >> 2)) * 4096 + i_start
                              + (size_t)(((2 * (lane & 3)) ^ ((lane >> 2) & 6)) * 8);
    const int ldst0 = wv * 4096;                  // byte offset within buffer

#define STAGE(bufsel, ioff)                                                             \
    do {                                                                                \
        _Pragma("unroll")                                                               \
        for (int s_ = 0; s_ < 4; ++s_)                                                  \
            GLOAD_LDS16(vsrc + (size_t)s_ * 65536 + (ioff),                             \
                        vlds + (bufsel) * 16384 + ldst0 + s_ * 1024);                   \
    } while (0)

    // PV A-frag: one b64 per (is, ct); row c = ct*16 + l15 (64B rows);
    // unit u = 4is+g, slot = u ^ (c&6) = u ^ (l15&6). ct stride 1024 bytes.
    const int rdA = l15 * 64 + ((g ^ (l15 & 6)) << 3);            // is = 0
    const int rdB = l15 * 64 + (((4 + g) ^ (l15 & 6)) << 3);      // is = 1

    const unsigned short* qp = qTb + (size_t)(i_start + l15) * 32 + g * 8;

    f32x4 oacc[16][2] = {};
    float l_acc0 = 0.0f, l_acc1 = 0.0f;
    const f32x4 zf = {0.f, 0.f, 0.f, 0.f};

    // prologue: stage tile 0 and load tile 0's q fragments
    STAGE(0, 0);
    short8 qa0 = *(const short8*)(qp);
    short8 qa1 = *(const short8*)(qp + 512);
    short8 qa2 = *(const short8*)(qp + 1024);
    short8 qa3 = *(const short8*)(qp + 1536);
    qp += 2048;
    __syncthreads();

    for (int t = 0; t < T; ++t) {
        const int cur = t & 1;
        if (t + 1 < T) STAGE(cur ^ 1, (t + 1) * 64);

        // ---- QK^T: 4 i-subtiles x 2 m-subtiles (bf16, q preloaded) ----
        f32x4 P[4][2];
        P[0][0] = MFMA16(qa0, qkB0, zf); P[0][1] = MFMA16(qa0, qkB1, zf);
        P[1][0] = MFMA16(qa1, qkB0, zf); P[1][1] = MFMA16(qa1, qkB1, zf);
        P[2][0] = MFMA16(qa2, qkB0, zf); P[2][1] = MFMA16(qa2, qkB1, zf);
        P[3][0] = MFMA16(qa3, qkB0, zf); P[3][1] = MFMA16(qa3, qkB1, zf);

        // ---- P = exp2(S); per-lane l sums ----
        float s00 = 0.f, s01 = 0.f, s10 = 0.f, s11 = 0.f;
#pragma unroll
        for (int it = 0; it < 4; ++it)
#pragma unroll
            for (int r = 0; r < 4; ++r) {
                P[it][0][r] = fexp2(P[it][0][r]);
                P[it][1][r] = fexp2(P[it][1][r]);
                if (it < 2) { s00 += P[it][0][r]; s01 += P[it][1][r]; }
                else        { s10 += P[it][0][r]; s11 += P[it][1][r]; }
            }
        l_acc0 += s00 + s10;
        l_acc1 += s01 + s11;

        // ---- pack P B-frags to fp8 (lane-local): frag(is,ms) bytes e<4 from subtile
        // 2is (r=e), e>=4 from subtile 2is+1 (r=e-4) ----
        const u32x2 w00 = {pk_fp8_4(P[0][0][0], P[0][0][1], P[0][0][2], P[0][0][3]),
                           pk_fp8_4(P[1][0][0], P[1][0][1], P[1][0][2], P[1][0][3])};
        const u32x2 w01 = {pk_fp8_4(P[0][1][0], P[0][1][1], P[0][1][2], P[0][1][3]),
                           pk_fp8_4(P[1][1][0], P[1][1][1], P[1][1][2], P[1][1][3])};
        const u32x2 w10 = {pk_fp8_4(P[2][0][0], P[2][0][1], P[2][0][2], P[2][0][3]),
                           pk_fp8_4(P[3][0][0], P[3][0][1], P[3][0][2], P[3][0][3])};
        const u32x2 w11 = {pk_fp8_4(P[2][1][0], P[2][1][1], P[2][1][2], P[2][1][3]),
                           pk_fp8_4(P[3][1][0], P[3][1][1], P[3][1][2], P[3][1][3])};
        const long pf00 = __builtin_bit_cast(long, w00);   // is=0, msub=0
        const long pf01 = __builtin_bit_cast(long, w01);   // is=0, msub=1
        const long pf10 = __builtin_bit_cast(long, w10);   // is=1, msub=0
        const long pf11 = __builtin_bit_cast(long, w11);   // is=1, msub=1

        // ---- prefetch next tile's q fragments (latency hides under PV) ----
        short8 qn0, qn1, qn2, qn3;
        if (t + 1 < T) {
            qn0 = *(const short8*)(qp);
            qn1 = *(const short8*)(qp + 512);
            qn2 = *(const short8*)(qp + 1024);
            qn3 = *(const short8*)(qp + 1536);
            qp += 2048;
        }

        // ---- PV: one b64 V read per (is, ct), each feeding 2 fp8 MFMAs ----
        const unsigned char* vbase = vlds + cur * 16384;
        const unsigned char* pA = vbase + rdA;
        const unsigned char* pB = vbase + rdB;
        __builtin_amdgcn_s_setprio(1);
#pragma unroll
        for (int ct = 0; ct < 16; ++ct) {
            const long va0 = __builtin_bit_cast(long, *(const u32x2*)(pA + ct * 1024));
            const long va1 = __builtin_bit_cast(long, *(const u32x2*)(pB + ct * 1024));
            oacc[ct][0] = MFMAF8(va0, pf00, oacc[ct][0]);
            oacc[ct][1] = MFMAF8(va0, pf01, oacc[ct][1]);
            oacc[ct][0] = MFMAF8(va1, pf10, oacc[ct][0]);
            oacc[ct][1] = MFMAF8(va1, pf11, oacc[ct][1]);
        }
        __builtin_amdgcn_s_setprio(0);

        if (t + 1 < T) {
            qa0 = qn0; qa1 = qn1; qa2 = qn2; qa3 = qn3;
            __syncthreads();
        }
    }
#undef STAGE

    // ---- epilogue: raw partial O (bf16) and per-m l sums ----
    unsigned short* Ob = Opart + (size_t)(sp * 4 + b) * 1048576;
#pragma unroll
    for (int ct = 0; ct < 16; ++ct)
#pragma unroll
        for (int r = 0; r < 4; ++r) {
            const int c = ct * 16 + g * 4 + r;
            Ob[(size_t)c * 4096 + m_base + l15]      = f2bf(oacc[ct][0][r]);
            Ob[(size_t)c * 4096 + m_base + 16 + l15] = f2bf(oacc[ct][1][r]);
        }
    float l0 = l_acc0, l1 = l_acc1;
    l0 += __shfl_xor(l0, 16); l0 += __shfl_xor(l0, 32);
    l1 += __shfl_xor(l1, 16); l1 += __shfl_xor(l1, 32);
    if (lane < 16) {
        const size_t mi = (size_t)(sp * 4 + b) * 4096 + m_base + l15;
        mll[mi]      = l0;
        mll[mi + 16] = l1;
    }
}

// ---------------- Kernel 3: combine partials (pure sum) + gamma*O/L + x ----------------
// grid: 4*256*4096 / (256 threads * 8 elements) = 2048 blocks
__global__ __launch_bounds__(256) void k_combine(const unsigned short* __restrict__ Opart,
                                                 const float* __restrict__ mll,
                                                 const float* __restrict__ x,
                                                 const float* __restrict__ gamma,
                                                 float* __restrict__ out, int S) {
    const size_t e0 = ((size_t)blockIdx.x * 256 + threadIdx.x) * 8;   // < 4,194,304
    const int m0 = (int)(e0 & 4095);
    const int b = (int)(e0 >> 20);

    float L[8] = {}, O[8] = {};
    for (int s = 0; s < S; ++s) {
        const size_t base = (size_t)(s * 4 + b) * 4096 + m0;
        const float4 la = *(const float4*)(mll + base);
        const float4 lc = *(const float4*)(mll + base + 4);
        const short8 op = *(const short8*)(Opart + (size_t)s * 4194304 + e0);
        L[0] += la.x; O[0] += bf2f((unsigned short)op[0]);
        L[1] += la.y; O[1] += bf2f((unsigned short)op[1]);
        L[2] += la.z; O[2] += bf2f((unsigned short)op[2]);
        L[3] += la.w; O[3] += bf2f((unsigned short)op[3]);
        L[4] += lc.x; O[4] += bf2f((unsigned short)op[4]);
        L[5] += lc.y; O[5] += bf2f((unsigned short)op[5]);
        L[6] += lc.z; O[6] += bf2f((unsigned short)op[6]);
        L[7] += lc.w; O[7] += bf2f((unsigned short)op[7]);
    }

    const float g0 = gamma[0];
    const float4 x0 = *(const float4*)(x + e0);
    const float4 x1 = *(const float4*)(x + e0 + 4);
    float4 o0, o1;
    o0.x = g0 * O[0] / L[0] + x0.x; o0.y = g0 * O[1] / L[1] + x0.y;
    o0.z = g0 * O[2] / L[2] + x0.z; o0.w = g0 * O[3] / L[3] + x0.w;
    o1.x = g0 * O[4] / L[4] + x1.x; o1.y = g0 * O[5] / L[5] + x1.y;
    o1.z = g0 * O[6] / L[6] + x1.z; o1.w = g0 * O[7] / L[7] + x1.w;
    *(float4*)(out + e0) = o0;
    *(float4*)(out + e0 + 4) = o1;
}

extern "C" void kernel_launch(void* const* d_in, const int* in_sizes, int n_in,
                              void* d_out, int out_size, void* d_ws, size_t ws_size,
                              hipStream_t stream) {
    (void)in_sizes; (void)n_in; (void)out_size;
    const float* x     = (const float*)d_in[0];
    const float* Wq    = (const float*)d_in[1];
    const float* bq    = (const float*)d_in[2];
    const float* Wk    = (const float*)d_in[3];
    const float* bk    = (const float*)d_in[4];
    const float* Wv    = (const float*)d_in[5];
    const float* bv    = (const float*)d_in[6];
    const float* gamma = (const float*)d_in[7];
    float* out = (float*)d_out;

    unsigned short* qT = (unsigned short*)d_ws;                       // 4*4096*32 bf16
    unsigned short* kT = qT + (size_t)4 * 4096 * 32;                  // 4*4096*32
    unsigned char* vp8 = (unsigned char*)(kT + (size_t)4 * 4096 * 32);  // 4*256*4096 B
    unsigned short* Wb = (unsigned short*)(vp8 + (size_t)4 * 256 * 4096);  // 81920 bf16
    unsigned short* Opart = Wb + 81920;                               // S * 4*256*4096 bf16

    // element budget (ush units): qT+kT + vp8(=2097152 ush) + Wb
    const size_t base_el = 2 * (size_t)4 * 4096 * 32 + 2097152 + 81920;
    auto need = [&](int s) {
        return (base_el + (size_t)s * 4194304) * 2 + (size_t)s * 16384 * 4;
    };
    const int S = (need(4) <= ws_size) ? 4 : (need(2) <= ws_size) ? 2 : 1;
    float* mll = (float*)(Opart + (size_t)S * 4194304);

    k_prepw<<<dim3(80), 256, 0, stream>>>(Wq, Wk, Wv, Wb);
    k_qkv<<<dim3(64, 4, 2), 256, 0, stream>>>(x, Wb, bq, bk, bv, qT, kT, vp8);
    k_attn<<<dim3(32, 4, S), 256, 0, stream>>>(qT, kT, vp8, Opart, mll, 4096 / S);
    k_combine<<<dim3(2048), 256, 0, stream>>>(Opart, mll, x, gamma, out, S);
}